// Round 5
// baseline (1445.014 us; speedup 1.0000x reference)
//
#include <hip/hip_runtime.h>
#include <hip/hip_bf16.h>

typedef unsigned int u32;
typedef unsigned short u16;

__device__ inline float b2f(u16 b) { return __uint_as_float((u32)b << 16); }
// element i of an external float array: f32 (fl=1) or packed bf16 (fl=0)
__device__ inline float ldext(const void* p, int fl, int i) {
    return fl ? ((const float*)p)[i] : b2f(((const u16*)p)[i]);
}

// ---------------------------------------------------------------------------
// flags[0]: edge stride (1 = int64 layout, 0 = int32)
// flags[1]: float inputs are f32 (1) or packed bf16 (0)
// flags[2]: E (edges per timestep), decided by probing data extent
__global__ __launch_bounds__(64) void detect_kernel(const int* __restrict__ eb,
                                                    const u32* __restrict__ xw,
                                                    int* __restrict__ flags,
                                                    int S, int n) {
    __shared__ int sh[64 * 3];
    int lane = threadIdx.x & 63;
    int zc = 0, explo = 0;
#pragma unroll
    for (int r = 0; r < 4; ++r) {
        int i = 64 * r + lane;
        zc += (eb[2 * i + 1] == 0) ? 1 : 0;   // int64: odd dwords are hi-words = 0
        u32 w = xw[i];
        int e = (int)((w >> 7) & 0xFF);       // exponent field of LOW half as bf16
        explo += (e >= 96 && e <= 140) ? 1 : 0;
    }
    sh[lane] = zc;
    sh[64 + lane] = explo;
    __syncthreads();
    int fl = 0;
    {
        int z = 0;
        for (int j = 0; j < 64; ++j) z += sh[j];
        fl = (z > 200) ? 1 : 0;   // wave-uniform
    }
    // probe logical indices [S/2, S/2+256): valid node ids => S counts logical
    // elements (E = S/4); garbage => S counts int32 words (E = S/8).
    int vc = 0;
#pragma unroll
    for (int r = 0; r < 4; ++r) {
        int li = S / 2 + 64 * r + lane;
        int v = fl ? eb[2 * li] : eb[li];
        vc += ((unsigned)v < (unsigned)n) ? 1 : 0;
    }
    sh[128 + lane] = vc;
    __syncthreads();
    if (lane == 0) {
        int vtot = 0, etot = 0;
        for (int j = 0; j < 64; ++j) vtot += sh[128 + j];
        for (int j = 0; j < 64; ++j) etot += sh[64 + j];
        flags[0] = fl;
        flags[1] = (etot >= 192) ? 0 : 1;   // bf16-packed signature else f32
        flags[2] = (vtot >= 240) ? (S / 4) : (S / 8);
    }
}

__device__ inline int load_edge(const int* eb, int fl, int idx) {
    return eb[fl ? (idx << 1) : idx];
}

// ---------------------------------------------------------------------------
__global__ __launch_bounds__(256) void deg_kernel(const int* __restrict__ eb,
                                                  const int* __restrict__ flags,
                                                  int t, int* __restrict__ deg, int n) {
    int E = flags[2];
    int e = blockIdx.x * 256 + threadIdx.x;
    if (e < E) {
        int base = t * 2 * E;
        unsigned d = (unsigned)load_edge(eb, flags[0], base + E + e);
        if (d < (unsigned)n) atomicAdd(&deg[d], 1);
    }
}

// ---------------------------------------------------------------------------
// 3-phase exclusive scan of deg -> off, plus cursor copy and dinv
__global__ __launch_bounds__(256) void scan_a(const int* __restrict__ deg,
                                              int* __restrict__ off,
                                              int* __restrict__ btot, int n) {
    __shared__ int tmp[256];
    int t = threadIdx.x;
    int i = blockIdx.x * 256 + t;
    int d = (i < n) ? deg[i] : 0;
    int val = d;
    tmp[t] = val;
    __syncthreads();
    for (int o = 1; o < 256; o <<= 1) {
        int add = (t >= o) ? tmp[t - o] : 0;
        __syncthreads();
        val += add;
        tmp[t] = val;
        __syncthreads();
    }
    if (i < n) off[i] = val - d;
    if (t == 255) btot[blockIdx.x] = val;
}

__global__ __launch_bounds__(256) void scan_b(int* __restrict__ btot, int nb) {
    __shared__ int tmp[256];
    int t = threadIdx.x;
    int d = (t < nb) ? btot[t] : 0;
    int val = d;
    tmp[t] = val;
    __syncthreads();
    for (int o = 1; o < 256; o <<= 1) {
        int add = (t >= o) ? tmp[t - o] : 0;
        __syncthreads();
        val += add;
        tmp[t] = val;
        __syncthreads();
    }
    if (t < nb) btot[t] = val - d;
}

__global__ __launch_bounds__(256) void scan_c(const int* __restrict__ deg,
                                              const int* __restrict__ btot,
                                              int* __restrict__ off,
                                              int* __restrict__ cursor,
                                              float* __restrict__ dinv, int n) {
    int i = blockIdx.x * 256 + threadIdx.x;
    if (i < n) {
        int o = off[i] + btot[blockIdx.x];
        off[i] = o;
        cursor[i] = o;
        dinv[i] = rsqrtf((float)(deg[i] + 1));  // +1 = self-loop
    }
}

// ---------------------------------------------------------------------------
__global__ __launch_bounds__(256) void fill_kernel(const int* __restrict__ eb,
                                                   const int* __restrict__ flags,
                                                   int t, int* __restrict__ cursor,
                                                   int* __restrict__ ssrc,
                                                   int n, int Emax) {
    int E = flags[2];
    int e = blockIdx.x * 256 + threadIdx.x;
    if (e < E) {
        int fl = flags[0];
        int base = t * 2 * E;
        unsigned s = (unsigned)load_edge(eb, fl, base + e);
        unsigned d = (unsigned)load_edge(eb, fl, base + E + e);
        if (s < (unsigned)n && d < (unsigned)n) {
            int pos = atomicAdd(&cursor[d], 1);
            if ((unsigned)pos < (unsigned)Emax) ssrc[pos] = (int)s;
        }
    }
}

// ---------------------------------------------------------------------------
// Simple, auditable GEMM: thread (v,c) computes
//   hs[v*128+c] = dinv[v] * sum_k X[v][k] * W[k][c]     (f32 accumulate)
// X: external (dtype flags[1]) if x_ext, else internal f32.
__global__ __launch_bounds__(256) void gemm_simple(const void* __restrict__ Xv,
                                                   size_t xoff,
                                                   const void* __restrict__ Wv,
                                                   const int* __restrict__ flags,
                                                   int x_ext,
                                                   const float* __restrict__ dinv,
                                                   float* __restrict__ hs, int n) {
    int idx = blockIdx.x * 256 + threadIdx.x;
    int v = idx >> 7;
    int c = idx & 127;
    if (v >= n) return;
    int ffl = flags[1];
    int xf = x_ext ? ffl : 1;   // internal buffers are f32
    size_t xbase = xoff + (size_t)v * 128;
    float acc = 0.f;
    if (xf) {
        const float* Xf = (const float*)Xv;
        for (int k = 0; k < 128; ++k)
            acc += Xf[xbase + k] * ldext(Wv, ffl, k * 128 + c);
    } else {
        const u16* Xb = (const u16*)Xv;
        for (int k = 0; k < 128; ++k)
            acc += b2f(Xb[xbase + k]) * ldext(Wv, ffl, k * 128 + c);
    }
    hs[(size_t)v * 128 + c] = acc * dinv[v];
}

// ---------------------------------------------------------------------------
// out[v] = act( dinv[v] * (hs[v] + sum_{u in in(v)} hs[u]) + bias )  (all f32)
// one wave per node; lane owns cols 2l, 2l+1 (float2).
__global__ __launch_bounds__(256) void gather_kernel(const float* __restrict__ hs,
                                                     const int* __restrict__ off,
                                                     const int* __restrict__ deg,
                                                     const int* __restrict__ ssrc,
                                                     const float* __restrict__ dinv,
                                                     const void* __restrict__ bias,
                                                     const int* __restrict__ flags,
                                                     float* __restrict__ outf,
                                                     int n, int relu) {
    int w = (blockIdx.x * 256 + threadIdx.x) >> 6;
    int lane = threadIdx.x & 63;
    if (w >= n) return;

    const float2* hs2 = (const float2*)hs;   // row stride 64 float2
    float2 a = hs2[(size_t)w * 64 + lane];   // self-loop term
    int i = off[w], end = i + deg[w];
    for (; i < end; ++i) {
        unsigned s = (unsigned)ssrc[i];
        if (s < (unsigned)n) {
            float2 v = hs2[(size_t)s * 64 + lane];
            a.x += v.x;
            a.y += v.y;
        }
    }
    int ffl = flags[1];
    float dv = dinv[w];
    float o0 = dv * a.x + ldext(bias, ffl, 2 * lane);
    float o1 = dv * a.y + ldext(bias, ffl, 2 * lane + 1);
    if (relu) {
        o0 = fmaxf(o0, 0.f);
        o1 = fmaxf(o1, 0.f);
    }
    ((float2*)outf)[(size_t)w * 64 + lane] = make_float2(o0, o1);
}

// ---------------------------------------------------------------------------
// importance[v] = sum_c final[v][c]*Wc[c] + bc   (f32 in, f32 out)
__global__ __launch_bounds__(256) void importance_kernel(const float* __restrict__ finalf,
                                                         const void* __restrict__ Wc,
                                                         const void* __restrict__ bc,
                                                         const int* __restrict__ flags,
                                                         float* __restrict__ outp, int n) {
    __shared__ float sh[256];
    int tid = threadIdx.x;
    int w = blockIdx.x * 4 + (tid >> 6);
    int lane = tid & 63;
    int ffl = flags[1];
    float contrib = 0.f;
    if (w < n) {
        float2 p = ((const float2*)finalf)[(size_t)w * 64 + lane];
        contrib = p.x * ldext(Wc, ffl, 2 * lane) + p.y * ldext(Wc, ffl, 2 * lane + 1);
    }
    sh[tid] = contrib;
    __syncthreads();
    if (lane == 0 && w < n) {
        float s = 0.f;
        for (int j = 0; j < 64; ++j) s += sh[(tid & 192) + j];
        outp[w] = s + ldext(bc, ffl, 0);
    }
}

// ---------------------------------------------------------------------------
extern "C" void kernel_launch(void* const* d_in, const int* in_sizes, int n_in,
                              void* d_out, int out_size, void* d_ws, size_t ws_size,
                              hipStream_t stream) {
    const int T = 2, C = 128;
    const int N = in_sizes[0] / (T * C);   // 50000
    const int S = in_sizes[1];             // edge buffer reported element count
    const int Emax = S / 4;                // upper bound on edges per timestep

    const void* x_seq = d_in[0];
    const int* edges = (const int*)d_in[1];
    const void* W1 = d_in[2];
    const void* b1 = d_in[3];
    const void* W2 = d_in[4];
    const void* b2 = d_in[5];
    const void* Wc = d_in[6];
    const void* bc = d_in[7];

    // d_out is FLOAT32 (reference output dtype): [imp N][h_t0 N*C][h_t1 N*C]
    float* out = (float*)d_out;
    float* R0 = out + N;
    float* R1 = out + N + (size_t)N * C;

    // workspace ~34 MB: CSR ints + one f32 feature buffer
    char* p = (char*)d_ws;
    auto alloc = [&](size_t bytes) {
        char* r = p;
        p += (bytes + 255) & ~(size_t)255;
        return r;
    };
    int nb = (N + 255) / 256;
    int* flags = (int*)alloc(256);
    int* deg = (int*)alloc((size_t)N * 4);
    int* cursor = (int*)alloc((size_t)N * 4);
    int* off = (int*)alloc((size_t)(N + 1) * 4);
    int* btot = (int*)alloc((size_t)nb * 4);
    float* dinv = (float*)alloc((size_t)N * 4);
    int* ssrc = (int*)alloc((size_t)Emax * 4);
    float* hsf = (float*)alloc((size_t)N * C * 4);  // f32 scaled GEMM output

    const int gE = (Emax + 255) / 256;
    const int gN4 = (N + 3) / 4;            // wave-per-node kernels
    const int gS = (N * C + 255) / 256;     // simple gemm: thread per (v,c)

    detect_kernel<<<1, 64, 0, stream>>>(edges, (const u32*)x_seq, flags, S, N);

    for (int t = 0; t < T; ++t) {
        float* Rt = (t == 0) ? R0 : R1;     // final output region for this t
        // --- CSR build (shared by both conv layers of this timestep) ---
        hipMemsetAsync(deg, 0, (size_t)N * 4, stream);
        deg_kernel<<<gE, 256, 0, stream>>>(edges, flags, t, deg, N);
        scan_a<<<nb, 256, 0, stream>>>(deg, off, btot, N);
        scan_b<<<1, 256, 0, stream>>>(btot, nb);
        scan_c<<<nb, 256, 0, stream>>>(deg, btot, off, cursor, dinv, N);
        fill_kernel<<<gE, 256, 0, stream>>>(edges, flags, t, cursor, ssrc, N, Emax);

        // --- layer 1: hsf = dinv*(X_t @ W1); hmid = relu(gather)+b1 -> Rt (scratch)
        gemm_simple<<<gS, 256, 0, stream>>>(x_seq, (size_t)t * N * C, W1, flags, 1,
                                            dinv, hsf, N);
        gather_kernel<<<gN4, 256, 0, stream>>>(hsf, off, deg, ssrc, dinv, b1, flags,
                                               Rt, N, 1);

        // --- layer 2: hsf = dinv*(hmid @ W2); Rt = gather + b2 (overwrites hmid)
        gemm_simple<<<gS, 256, 0, stream>>>(Rt, 0, W2, flags, 0, dinv, hsf, N);
        gather_kernel<<<gN4, 256, 0, stream>>>(hsf, off, deg, ssrc, dinv, b2, flags,
                                               Rt, N, 0);
    }

    importance_kernel<<<gN4, 256, 0, stream>>>(R1, Wc, bc, flags, out, N);
}

// Round 6
// 1295.263 us; speedup vs baseline: 1.1156x; 1.1156x over previous
//
#include <hip/hip_runtime.h>
#include <hip/hip_bf16.h>

typedef unsigned int u32;
typedef unsigned short u16;

__device__ inline float b2f(u16 b) { return __uint_as_float((u32)b << 16); }
// element i of an external float array: f32 (fl=1) or packed bf16 (fl=0)
__device__ inline float ldext(const void* p, int fl, int i) {
    return fl ? ((const float*)p)[i] : b2f(((const u16*)p)[i]);
}

// ---------------------------------------------------------------------------
// flags[0]: edge stride (1 = int64 layout, 0 = int32)
// flags[1]: float inputs are f32 (1) or packed bf16 (0)
// flags[2]: E (edges per timestep), decided by probing data extent
__global__ __launch_bounds__(64) void detect_kernel(const int* __restrict__ eb,
                                                    const u32* __restrict__ xw,
                                                    int* __restrict__ flags,
                                                    int S, int n) {
    __shared__ int sh[64 * 3];
    int lane = threadIdx.x & 63;
    int zc = 0, explo = 0;
#pragma unroll
    for (int r = 0; r < 4; ++r) {
        int i = 64 * r + lane;
        zc += (eb[2 * i + 1] == 0) ? 1 : 0;   // int64: odd dwords are hi-words = 0
        u32 w = xw[i];
        int e = (int)((w >> 7) & 0xFF);       // exponent field of LOW half as bf16
        explo += (e >= 96 && e <= 140) ? 1 : 0;
    }
    sh[lane] = zc;
    sh[64 + lane] = explo;
    __syncthreads();
    int fl = 0;
    {
        int z = 0;
        for (int j = 0; j < 64; ++j) z += sh[j];
        fl = (z > 200) ? 1 : 0;   // wave-uniform
    }
    // probe logical indices [S/2, S/2+256): valid node ids => S counts logical
    // elements (E = S/4); garbage => S counts int32 words (E = S/8).
    int vc = 0;
#pragma unroll
    for (int r = 0; r < 4; ++r) {
        int li = S / 2 + 64 * r + lane;
        int v = fl ? eb[2 * li] : eb[li];
        vc += ((unsigned)v < (unsigned)n) ? 1 : 0;
    }
    sh[128 + lane] = vc;
    __syncthreads();
    if (lane == 0) {
        int vtot = 0, etot = 0;
        for (int j = 0; j < 64; ++j) vtot += sh[128 + j];
        for (int j = 0; j < 64; ++j) etot += sh[64 + j];
        flags[0] = fl;
        flags[1] = (etot >= 192) ? 0 : 1;   // bf16-packed signature else f32
        flags[2] = (vtot >= 240) ? (S / 4) : (S / 8);
    }
}

__device__ inline int load_edge(const int* eb, int fl, int idx) {
    return eb[fl ? (idx << 1) : idx];
}

// ---------------------------------------------------------------------------
__global__ __launch_bounds__(256) void deg_kernel(const int* __restrict__ eb,
                                                  const int* __restrict__ flags,
                                                  int t, int* __restrict__ deg, int n) {
    int E = flags[2];
    int e = blockIdx.x * 256 + threadIdx.x;
    if (e < E) {
        int base = t * 2 * E;
        unsigned d = (unsigned)load_edge(eb, flags[0], base + E + e);
        if (d < (unsigned)n) atomicAdd(&deg[d], 1);
    }
}

// ---------------------------------------------------------------------------
// 3-phase exclusive scan of deg -> off, plus cursor copy and dinv
__global__ __launch_bounds__(256) void scan_a(const int* __restrict__ deg,
                                              int* __restrict__ off,
                                              int* __restrict__ btot, int n) {
    __shared__ int tmp[256];
    int t = threadIdx.x;
    int i = blockIdx.x * 256 + t;
    int d = (i < n) ? deg[i] : 0;
    int val = d;
    tmp[t] = val;
    __syncthreads();
    for (int o = 1; o < 256; o <<= 1) {
        int add = (t >= o) ? tmp[t - o] : 0;
        __syncthreads();
        val += add;
        tmp[t] = val;
        __syncthreads();
    }
    if (i < n) off[i] = val - d;
    if (t == 255) btot[blockIdx.x] = val;
}

__global__ __launch_bounds__(256) void scan_b(int* __restrict__ btot, int nb) {
    __shared__ int tmp[256];
    int t = threadIdx.x;
    int d = (t < nb) ? btot[t] : 0;
    int val = d;
    tmp[t] = val;
    __syncthreads();
    for (int o = 1; o < 256; o <<= 1) {
        int add = (t >= o) ? tmp[t - o] : 0;
        __syncthreads();
        val += add;
        tmp[t] = val;
        __syncthreads();
    }
    if (t < nb) btot[t] = val - d;
}

__global__ __launch_bounds__(256) void scan_c(const int* __restrict__ deg,
                                              const int* __restrict__ btot,
                                              int* __restrict__ off,
                                              int* __restrict__ cursor,
                                              float* __restrict__ dinv, int n) {
    int i = blockIdx.x * 256 + threadIdx.x;
    if (i < n) {
        int o = off[i] + btot[blockIdx.x];
        off[i] = o;
        cursor[i] = o;
        dinv[i] = rsqrtf((float)(deg[i] + 1));  // +1 = self-loop
    }
}

// ---------------------------------------------------------------------------
__global__ __launch_bounds__(256) void fill_kernel(const int* __restrict__ eb,
                                                   const int* __restrict__ flags,
                                                   int t, int* __restrict__ cursor,
                                                   int* __restrict__ ssrc,
                                                   int n, int Emax) {
    int E = flags[2];
    int e = blockIdx.x * 256 + threadIdx.x;
    if (e < E) {
        int fl = flags[0];
        int base = t * 2 * E;
        unsigned s = (unsigned)load_edge(eb, fl, base + e);
        unsigned d = (unsigned)load_edge(eb, fl, base + E + e);
        if (s < (unsigned)n && d < (unsigned)n) {
            int pos = atomicAdd(&cursor[d], 1);
            if ((unsigned)pos < (unsigned)Emax) ssrc[pos] = (int)s;
        }
    }
}

// ---------------------------------------------------------------------------
// Tiled GEMM: hs[v][c] = dinv[v] * sum_k X[v][k] * W[k][c]   (f32 accumulate)
// Block 256 = 4 waves; wave handles 16 nodes x 128 cols (lane c, c+64).
// W staged in LDS as f32, K-tiled 64 (32 KB). X rows: wave-uniform float4
// loads (L1 broadcast). LDS reads: consecutive lanes -> consecutive banks.
__global__ __launch_bounds__(256) void gemm_tiled(const void* __restrict__ Xv,
                                                  size_t xoff,
                                                  const void* __restrict__ Wv,
                                                  const int* __restrict__ flags,
                                                  int x_ext,
                                                  const float* __restrict__ dinv,
                                                  float* __restrict__ hs, int n) {
    __shared__ float Ws[64 * 128];  // 32 KB: W[kt..kt+64)[0..128)
    const int ffl = flags[1];
    const int xf = x_ext ? ffl : 1;  // internal buffers are f32

    int wave = threadIdx.x >> 6;
    int lane = threadIdx.x & 63;
    int node0 = (blockIdx.x * 4 + wave) * 16;
    const int c = lane;

    int nodeid[16];
#pragma unroll
    for (int nn = 0; nn < 16; ++nn) {
        int node = node0 + nn;
        nodeid[nn] = (node < n) ? node : (n - 1);  // clamp; store is guarded
    }

    float acc0[16], acc1[16];
#pragma unroll
    for (int nn = 0; nn < 16; ++nn) { acc0[nn] = 0.f; acc1[nn] = 0.f; }

    for (int kt = 0; kt < 128; kt += 64) {
        __syncthreads();  // previous tile fully consumed
        for (int i = threadIdx.x; i < 64 * 128; i += 256)
            Ws[i] = ldext(Wv, ffl, kt * 128 + i);
        __syncthreads();

        if (node0 < n) {
            if (xf) {
                const float* Xf = (const float*)Xv;
                for (int q = 0; q < 16; ++q) {
                    float w0[4], w1[4];
#pragma unroll
                    for (int j = 0; j < 4; ++j) {
                        w0[j] = Ws[(4 * q + j) * 128 + c];
                        w1[j] = Ws[(4 * q + j) * 128 + c + 64];
                    }
#pragma unroll
                    for (int nn = 0; nn < 16; ++nn) {
                        float4 xv = *(const float4*)(Xf + xoff +
                                                     (size_t)nodeid[nn] * 128 + kt + 4 * q);
                        acc0[nn] += xv.x * w0[0] + xv.y * w0[1] + xv.z * w0[2] + xv.w * w0[3];
                        acc1[nn] += xv.x * w1[0] + xv.y * w1[1] + xv.z * w1[2] + xv.w * w1[3];
                    }
                }
            } else {
                const u16* Xb = (const u16*)Xv;
                for (int q = 0; q < 16; ++q) {
                    float w0[4], w1[4];
#pragma unroll
                    for (int j = 0; j < 4; ++j) {
                        w0[j] = Ws[(4 * q + j) * 128 + c];
                        w1[j] = Ws[(4 * q + j) * 128 + c + 64];
                    }
#pragma unroll
                    for (int nn = 0; nn < 16; ++nn) {
                        uint2 xp = *(const uint2*)(Xb + xoff +
                                                   (size_t)nodeid[nn] * 128 + kt + 4 * q);
                        float x0 = __uint_as_float(xp.x << 16);
                        float x1 = __uint_as_float(xp.x & 0xffff0000u);
                        float x2 = __uint_as_float(xp.y << 16);
                        float x3 = __uint_as_float(xp.y & 0xffff0000u);
                        acc0[nn] += x0 * w0[0] + x1 * w0[1] + x2 * w0[2] + x3 * w0[3];
                        acc1[nn] += x0 * w1[0] + x1 * w1[1] + x2 * w1[2] + x3 * w1[3];
                    }
                }
            }
        }
    }

#pragma unroll
    for (int nn = 0; nn < 16; ++nn) {
        int node = node0 + nn;
        if (node < n) {
            float dv = dinv[node];
            hs[(size_t)node * 128 + c] = acc0[nn] * dv;
            hs[(size_t)node * 128 + c + 64] = acc1[nn] * dv;
        }
    }
}

// ---------------------------------------------------------------------------
// out[v] = act( dinv[v] * (hs[v] + sum_{u in in(v)} hs[u]) + bias )  (all f32)
// one wave per node; lane owns cols 2l, 2l+1 (float2). Edge loop unrolled x4
// with independent partials for memory-level parallelism.
__global__ __launch_bounds__(256) void gather_kernel(const float* __restrict__ hs,
                                                     const int* __restrict__ off,
                                                     const int* __restrict__ deg,
                                                     const int* __restrict__ ssrc,
                                                     const float* __restrict__ dinv,
                                                     const void* __restrict__ bias,
                                                     const int* __restrict__ flags,
                                                     float* __restrict__ outf,
                                                     int n, int relu) {
    int w = (blockIdx.x * 256 + threadIdx.x) >> 6;
    int lane = threadIdx.x & 63;
    if (w >= n) return;

    const float2* hs2 = (const float2*)hs;   // row stride 64 float2
    float2 a = hs2[(size_t)w * 64 + lane];   // self-loop term
    int i = off[w];
    int end = i + deg[w];
    unsigned nm1 = (unsigned)(n - 1);

    float ax1 = 0.f, ay1 = 0.f;
    for (; i + 4 <= end; i += 4) {
        unsigned s0 = (unsigned)ssrc[i];     if (s0 > nm1) s0 = 0;
        unsigned s1 = (unsigned)ssrc[i + 1]; if (s1 > nm1) s1 = 0;
        unsigned s2 = (unsigned)ssrc[i + 2]; if (s2 > nm1) s2 = 0;
        unsigned s3 = (unsigned)ssrc[i + 3]; if (s3 > nm1) s3 = 0;
        float2 v0 = hs2[(size_t)s0 * 64 + lane];
        float2 v1 = hs2[(size_t)s1 * 64 + lane];
        float2 v2 = hs2[(size_t)s2 * 64 + lane];
        float2 v3 = hs2[(size_t)s3 * 64 + lane];
        a.x += v0.x + v1.x;
        a.y += v0.y + v1.y;
        ax1 += v2.x + v3.x;
        ay1 += v2.y + v3.y;
    }
    for (; i < end; ++i) {
        unsigned s = (unsigned)ssrc[i];
        if (s > nm1) s = 0;
        float2 v = hs2[(size_t)s * 64 + lane];
        a.x += v.x;
        a.y += v.y;
    }
    a.x += ax1;
    a.y += ay1;

    int ffl = flags[1];
    float dv = dinv[w];
    float o0 = dv * a.x + ldext(bias, ffl, 2 * lane);
    float o1 = dv * a.y + ldext(bias, ffl, 2 * lane + 1);
    if (relu) {
        o0 = fmaxf(o0, 0.f);
        o1 = fmaxf(o1, 0.f);
    }
    ((float2*)outf)[(size_t)w * 64 + lane] = make_float2(o0, o1);
}

// ---------------------------------------------------------------------------
// importance[v] = sum_c final[v][c]*Wc[c] + bc   (f32 in, f32 out)
__global__ __launch_bounds__(256) void importance_kernel(const float* __restrict__ finalf,
                                                         const void* __restrict__ Wc,
                                                         const void* __restrict__ bc,
                                                         const int* __restrict__ flags,
                                                         float* __restrict__ outp, int n) {
    __shared__ float sh[256];
    int tid = threadIdx.x;
    int w = blockIdx.x * 4 + (tid >> 6);
    int lane = tid & 63;
    int ffl = flags[1];
    float contrib = 0.f;
    if (w < n) {
        float2 p = ((const float2*)finalf)[(size_t)w * 64 + lane];
        contrib = p.x * ldext(Wc, ffl, 2 * lane) + p.y * ldext(Wc, ffl, 2 * lane + 1);
    }
    sh[tid] = contrib;
    __syncthreads();
    if (lane == 0 && w < n) {
        float s = 0.f;
        for (int j = 0; j < 64; ++j) s += sh[(tid & 192) + j];
        outp[w] = s + ldext(bc, ffl, 0);
    }
}

// ---------------------------------------------------------------------------
extern "C" void kernel_launch(void* const* d_in, const int* in_sizes, int n_in,
                              void* d_out, int out_size, void* d_ws, size_t ws_size,
                              hipStream_t stream) {
    const int T = 2, C = 128;
    const int N = in_sizes[0] / (T * C);   // 50000
    const int S = in_sizes[1];             // edge buffer reported element count
    const int Emax = S / 4;                // upper bound on edges per timestep

    const void* x_seq = d_in[0];
    const int* edges = (const int*)d_in[1];
    const void* W1 = d_in[2];
    const void* b1 = d_in[3];
    const void* W2 = d_in[4];
    const void* b2 = d_in[5];
    const void* Wc = d_in[6];
    const void* bc = d_in[7];

    // d_out is FLOAT32 (reference output dtype): [imp N][h_t0 N*C][h_t1 N*C]
    float* out = (float*)d_out;
    float* R0 = out + N;
    float* R1 = out + N + (size_t)N * C;

    // workspace ~34 MB: CSR ints + one f32 feature buffer
    char* p = (char*)d_ws;
    auto alloc = [&](size_t bytes) {
        char* r = p;
        p += (bytes + 255) & ~(size_t)255;
        return r;
    };
    int nb = (N + 255) / 256;
    int* flags = (int*)alloc(256);
    int* deg = (int*)alloc((size_t)N * 4);
    int* cursor = (int*)alloc((size_t)N * 4);
    int* off = (int*)alloc((size_t)(N + 1) * 4);
    int* btot = (int*)alloc((size_t)nb * 4);
    float* dinv = (float*)alloc((size_t)N * 4);
    int* ssrc = (int*)alloc((size_t)Emax * 4);
    float* hsf = (float*)alloc((size_t)N * C * 4);  // f32 scaled GEMM output

    const int gE = (Emax + 255) / 256;
    const int gN4 = (N + 3) / 4;            // wave-per-node kernels
    const int gG = (N + 63) / 64;           // tiled gemm: block per 64 nodes

    detect_kernel<<<1, 64, 0, stream>>>(edges, (const u32*)x_seq, flags, S, N);

    for (int t = 0; t < T; ++t) {
        float* Rt = (t == 0) ? R0 : R1;     // final output region for this t
        // --- CSR build (shared by both conv layers of this timestep) ---
        hipMemsetAsync(deg, 0, (size_t)N * 4, stream);
        deg_kernel<<<gE, 256, 0, stream>>>(edges, flags, t, deg, N);
        scan_a<<<nb, 256, 0, stream>>>(deg, off, btot, N);
        scan_b<<<1, 256, 0, stream>>>(btot, nb);
        scan_c<<<nb, 256, 0, stream>>>(deg, btot, off, cursor, dinv, N);
        fill_kernel<<<gE, 256, 0, stream>>>(edges, flags, t, cursor, ssrc, N, Emax);

        // --- layer 1: hsf = dinv*(X_t @ W1); hmid = relu(gather)+b1 -> Rt (scratch)
        gemm_tiled<<<gG, 256, 0, stream>>>(x_seq, (size_t)t * N * C, W1, flags, 1,
                                           dinv, hsf, N);
        gather_kernel<<<gN4, 256, 0, stream>>>(hsf, off, deg, ssrc, dinv, b1, flags,
                                               Rt, N, 1);

        // --- layer 2: hsf = dinv*(hmid @ W2); Rt = gather + b2 (overwrites hmid)
        gemm_tiled<<<gG, 256, 0, stream>>>(Rt, 0, W2, flags, 0, dinv, hsf, N);
        gather_kernel<<<gN4, 256, 0, stream>>>(hsf, off, deg, ssrc, dinv, b2, flags,
                                               Rt, N, 0);
    }

    importance_kernel<<<gN4, 256, 0, stream>>>(R1, Wc, bc, flags, out, N);
}

// Round 7
// 519.216 us; speedup vs baseline: 2.7831x; 2.4947x over previous
//
#include <hip/hip_runtime.h>
#include <hip/hip_bf16.h>

typedef unsigned int u32;
typedef unsigned short u16;
typedef __bf16 bf16x8 __attribute__((ext_vector_type(8)));
typedef short short8 __attribute__((ext_vector_type(8)));
typedef float floatx4 __attribute__((ext_vector_type(4)));

__device__ inline float b2f(u16 b) { return __uint_as_float((u32)b << 16); }
__device__ inline float lo2f(u32 p) { return __uint_as_float(p << 16); }
__device__ inline float hi2f(u32 p) { return __uint_as_float(p & 0xffff0000u); }
__device__ inline u16 f2bs(float f) {   // RNE f32 -> bf16 bits
    __hip_bfloat16 h = __float2bfloat16(f);
    return *reinterpret_cast<u16*>(&h);
}
// element i of an external float array: f32 (fl=1) or packed bf16 (fl=0)
__device__ inline float ldext(const void* p, int fl, int i) {
    return fl ? ((const float*)p)[i] : b2f(((const u16*)p)[i]);
}

// ---------------------------------------------------------------------------
// flags[0]: edge stride (1 = int64 layout, 0 = int32)
// flags[1]: float inputs are f32 (1) or packed bf16 (0)
// flags[2]: E (edges per timestep), decided by probing data extent
__global__ __launch_bounds__(64) void detect_kernel(const int* __restrict__ eb,
                                                    const u32* __restrict__ xw,
                                                    int* __restrict__ flags,
                                                    int S, int n) {
    __shared__ int sh[64 * 3];
    int lane = threadIdx.x & 63;
    int zc = 0, explo = 0;
#pragma unroll
    for (int r = 0; r < 4; ++r) {
        int i = 64 * r + lane;
        zc += (eb[2 * i + 1] == 0) ? 1 : 0;   // int64: odd dwords are hi-words = 0
        u32 w = xw[i];
        int e = (int)((w >> 7) & 0xFF);       // exponent field of LOW half as bf16
        explo += (e >= 96 && e <= 140) ? 1 : 0;
    }
    sh[lane] = zc;
    sh[64 + lane] = explo;
    __syncthreads();
    int fl = 0;
    {
        int z = 0;
        for (int j = 0; j < 64; ++j) z += sh[j];
        fl = (z > 200) ? 1 : 0;   // wave-uniform
    }
    // probe logical indices [S/2, S/2+256): valid node ids => S counts logical
    // elements (E = S/4); garbage => S counts int32 words (E = S/8).
    int vc = 0;
#pragma unroll
    for (int r = 0; r < 4; ++r) {
        int li = S / 2 + 64 * r + lane;
        int v = fl ? eb[2 * li] : eb[li];
        vc += ((unsigned)v < (unsigned)n) ? 1 : 0;
    }
    sh[128 + lane] = vc;
    __syncthreads();
    if (lane == 0) {
        int vtot = 0, etot = 0;
        for (int j = 0; j < 64; ++j) vtot += sh[128 + j];
        for (int j = 0; j < 64; ++j) etot += sh[64 + j];
        flags[0] = fl;
        flags[1] = (etot >= 192) ? 0 : 1;   // bf16-packed signature else f32
        flags[2] = (vtot >= 240) ? (S / 4) : (S / 8);
    }
}

__device__ inline int load_edge(const int* eb, int fl, int idx) {
    return eb[fl ? (idx << 1) : idx];
}

// ---------------------------------------------------------------------------
__global__ __launch_bounds__(256) void deg_kernel(const int* __restrict__ eb,
                                                  const int* __restrict__ flags,
                                                  int t, int* __restrict__ deg, int n) {
    int E = flags[2];
    int e = blockIdx.x * 256 + threadIdx.x;
    if (e < E) {
        int base = t * 2 * E;
        unsigned d = (unsigned)load_edge(eb, flags[0], base + E + e);
        if (d < (unsigned)n) atomicAdd(&deg[d], 1);
    }
}

// ---------------------------------------------------------------------------
// 3-phase exclusive scan of deg -> off, plus cursor copy and dinv
__global__ __launch_bounds__(256) void scan_a(const int* __restrict__ deg,
                                              int* __restrict__ off,
                                              int* __restrict__ btot, int n) {
    __shared__ int tmp[256];
    int t = threadIdx.x;
    int i = blockIdx.x * 256 + t;
    int d = (i < n) ? deg[i] : 0;
    int val = d;
    tmp[t] = val;
    __syncthreads();
    for (int o = 1; o < 256; o <<= 1) {
        int add = (t >= o) ? tmp[t - o] : 0;
        __syncthreads();
        val += add;
        tmp[t] = val;
        __syncthreads();
    }
    if (i < n) off[i] = val - d;
    if (t == 255) btot[blockIdx.x] = val;
}

__global__ __launch_bounds__(256) void scan_b(int* __restrict__ btot, int nb) {
    __shared__ int tmp[256];
    int t = threadIdx.x;
    int d = (t < nb) ? btot[t] : 0;
    int val = d;
    tmp[t] = val;
    __syncthreads();
    for (int o = 1; o < 256; o <<= 1) {
        int add = (t >= o) ? tmp[t - o] : 0;
        __syncthreads();
        val += add;
        tmp[t] = val;
        __syncthreads();
    }
    if (t < nb) btot[t] = val - d;
}

__global__ __launch_bounds__(256) void scan_c(const int* __restrict__ deg,
                                              const int* __restrict__ btot,
                                              int* __restrict__ off,
                                              int* __restrict__ cursor,
                                              float* __restrict__ dinv, int n) {
    int i = blockIdx.x * 256 + threadIdx.x;
    if (i < n) {
        int o = off[i] + btot[blockIdx.x];
        off[i] = o;
        cursor[i] = o;
        dinv[i] = rsqrtf((float)(deg[i] + 1));  // +1 = self-loop
    }
}

// ---------------------------------------------------------------------------
__global__ __launch_bounds__(256) void fill_kernel(const int* __restrict__ eb,
                                                   const int* __restrict__ flags,
                                                   int t, int* __restrict__ cursor,
                                                   int* __restrict__ ssrc,
                                                   int n, int Emax) {
    int E = flags[2];
    int e = blockIdx.x * 256 + threadIdx.x;
    if (e < E) {
        int fl = flags[0];
        int base = t * 2 * E;
        unsigned s = (unsigned)load_edge(eb, fl, base + e);
        unsigned d = (unsigned)load_edge(eb, fl, base + E + e);
        if (s < (unsigned)n && d < (unsigned)n) {
            int pos = atomicAdd(&cursor[d], 1);
            if ((unsigned)pos < (unsigned)Emax) ssrc[pos] = (int)s;
        }
    }
}

// ---------------------------------------------------------------------------
// W (128x128, external dtype) -> Wt bf16 transposed: Wt[c*128+k] = bf16(W[k][c])
__global__ __launch_bounds__(256) void prep_w(const void* __restrict__ W,
                                              const int* __restrict__ flags,
                                              u16* __restrict__ Wt) {
    int tid = blockIdx.x * 256 + threadIdx.x;
    if (tid < 128 * 128) {
        int c = tid >> 7, k = tid & 127;
        Wt[c * 128 + k] = f2bs(ldext(W, flags[1], k * 128 + c));
    }
}

// ---------------------------------------------------------------------------
// MFMA GEMM: hs[v][c] = bf16( dinv[v] * sum_k X[v][k] * W[k][c] )
// mfma_f32_16x16x32_bf16. Block = 4 waves, 64 rows/block; wave = 16 rows x
// 128 cols = 8 col-tiles x 4 K-steps = 32 MFMAs. Wt staged in LDS, row
// stride 136 bf16 (2-way bank aliasing only -> free).
// Verified layouts (learn_hip m89/m91): A[m=lane&15][k=quad*8+j],
// B[n=lane&15][k=quad*8+j], C/D col=lane&15, row=quad*4+reg.
__global__ __launch_bounds__(256) void gemm_mfma(const void* __restrict__ Xv,
                                                 size_t xoff, int x_ext,
                                                 const u16* __restrict__ Wt,
                                                 const int* __restrict__ flags,
                                                 const float* __restrict__ dinv,
                                                 u16* __restrict__ hs, int n) {
    __shared__ u16 Ws[128 * 136];  // Wt[c][k], padded stride 136
    {
        u32* wsu = (u32*)Ws;
        const u32* wtu = (const u32*)Wt;
        for (int i = threadIdx.x; i < 128 * 64; i += 256) {
            int c = i >> 6, kk = i & 63;
            wsu[c * 68 + kk] = wtu[i];
        }
    }
    __syncthreads();

    const int wave = threadIdx.x >> 6;
    const int lane = threadIdx.x & 63;
    const int m = lane & 15;
    const int quad = lane >> 4;
    const int node0 = blockIdx.x * 64 + wave * 16;
    if (node0 >= n) return;

    const int xf32 = x_ext ? flags[1] : 0;   // internal buffers are bf16
    int va = node0 + m;
    if (va > n - 1) va = n - 1;              // clamp; stores guarded

    floatx4 acc[8];
#pragma unroll
    for (int t = 0; t < 8; ++t) acc[t] = (floatx4){0.f, 0.f, 0.f, 0.f};

#pragma unroll
    for (int ks = 0; ks < 4; ++ks) {
        bf16x8 a;
        if (xf32) {
            const float* Xf = (const float*)Xv + xoff + (size_t)va * 128 + ks * 32 + quad * 8;
            float4 x0 = *(const float4*)Xf;
            float4 x1 = *(const float4*)(Xf + 4);
            short8 as;
            as[0] = (short)f2bs(x0.x); as[1] = (short)f2bs(x0.y);
            as[2] = (short)f2bs(x0.z); as[3] = (short)f2bs(x0.w);
            as[4] = (short)f2bs(x1.x); as[5] = (short)f2bs(x1.y);
            as[6] = (short)f2bs(x1.z); as[7] = (short)f2bs(x1.w);
            a = __builtin_bit_cast(bf16x8, as);
        } else {
            const u16* Xb = (const u16*)Xv + xoff + (size_t)va * 128 + ks * 32 + quad * 8;
            a = *(const bf16x8*)Xb;
        }
#pragma unroll
        for (int t = 0; t < 8; ++t) {
            const bf16x8 b = *(const bf16x8*)(Ws + (16 * t + m) * 136 + ks * 32 + quad * 8);
            acc[t] = __builtin_amdgcn_mfma_f32_16x16x32_bf16(a, b, acc[t], 0, 0, 0);
        }
    }

#pragma unroll
    for (int r = 0; r < 4; ++r) {
        int v = node0 + quad * 4 + r;
        if (v < n) {
            float dv = dinv[v];
#pragma unroll
            for (int t = 0; t < 8; ++t)
                hs[(size_t)v * 128 + 16 * t + m] = f2bs(acc[t][r] * dv);
        }
    }
}

// ---------------------------------------------------------------------------
// out[v] = act( dinv[v] * (hs[v] + sum_{u in in(v)} hs[u]) + bias )
// hs: packed bf16 (lane reads u32 = 2 cols). Output: f32 (outf) or bf16 (outb).
__global__ __launch_bounds__(256) void gather_kernel(const u16* __restrict__ hs,
                                                     const int* __restrict__ off,
                                                     const int* __restrict__ deg,
                                                     const int* __restrict__ ssrc,
                                                     const float* __restrict__ dinv,
                                                     const void* __restrict__ bias,
                                                     const int* __restrict__ flags,
                                                     float* __restrict__ outf,
                                                     u16* __restrict__ outb,
                                                     int n, int relu) {
    int w = (blockIdx.x * 256 + threadIdx.x) >> 6;
    int lane = threadIdx.x & 63;
    if (w >= n) return;

    const u32* hsu = (const u32*)hs;         // row stride 64 u32
    u32 p = hsu[(size_t)w * 64 + lane];      // self-loop term
    float ax = lo2f(p), ay = hi2f(p);
    int i = off[w];
    int end = i + deg[w];
    unsigned nm1 = (unsigned)(n - 1);

    float ax1 = 0.f, ay1 = 0.f;
    for (; i + 4 <= end; i += 4) {
        unsigned s0 = (unsigned)ssrc[i];     if (s0 > nm1) s0 = 0;
        unsigned s1 = (unsigned)ssrc[i + 1]; if (s1 > nm1) s1 = 0;
        unsigned s2 = (unsigned)ssrc[i + 2]; if (s2 > nm1) s2 = 0;
        unsigned s3 = (unsigned)ssrc[i + 3]; if (s3 > nm1) s3 = 0;
        u32 v0 = hsu[(size_t)s0 * 64 + lane];
        u32 v1 = hsu[(size_t)s1 * 64 + lane];
        u32 v2 = hsu[(size_t)s2 * 64 + lane];
        u32 v3 = hsu[(size_t)s3 * 64 + lane];
        ax += lo2f(v0) + lo2f(v1);
        ay += hi2f(v0) + hi2f(v1);
        ax1 += lo2f(v2) + lo2f(v3);
        ay1 += hi2f(v2) + hi2f(v3);
    }
    for (; i < end; ++i) {
        unsigned s = (unsigned)ssrc[i];
        if (s > nm1) s = 0;
        u32 v = hsu[(size_t)s * 64 + lane];
        ax += lo2f(v);
        ay += hi2f(v);
    }
    ax += ax1;
    ay += ay1;

    int ffl = flags[1];
    float dv = dinv[w];
    float o0 = dv * ax + ldext(bias, ffl, 2 * lane);
    float o1 = dv * ay + ldext(bias, ffl, 2 * lane + 1);
    if (relu) {
        o0 = fmaxf(o0, 0.f);
        o1 = fmaxf(o1, 0.f);
    }
    if (outf) ((float2*)outf)[(size_t)w * 64 + lane] = make_float2(o0, o1);
    else ((u32*)outb)[(size_t)w * 64 + lane] = (u32)f2bs(o0) | ((u32)f2bs(o1) << 16);
}

// ---------------------------------------------------------------------------
// importance[v] = sum_c final[v][c]*Wc[c] + bc   (f32 in, f32 out)
__global__ __launch_bounds__(256) void importance_kernel(const float* __restrict__ finalf,
                                                         const void* __restrict__ Wc,
                                                         const void* __restrict__ bc,
                                                         const int* __restrict__ flags,
                                                         float* __restrict__ outp, int n) {
    __shared__ float sh[256];
    int tid = threadIdx.x;
    int w = blockIdx.x * 4 + (tid >> 6);
    int lane = tid & 63;
    int ffl = flags[1];
    float contrib = 0.f;
    if (w < n) {
        float2 p = ((const float2*)finalf)[(size_t)w * 64 + lane];
        contrib = p.x * ldext(Wc, ffl, 2 * lane) + p.y * ldext(Wc, ffl, 2 * lane + 1);
    }
    sh[tid] = contrib;
    __syncthreads();
    if (lane == 0 && w < n) {
        float s = 0.f;
        for (int j = 0; j < 64; ++j) s += sh[(tid & 192) + j];
        outp[w] = s + ldext(bc, ffl, 0);
    }
}

// ---------------------------------------------------------------------------
extern "C" void kernel_launch(void* const* d_in, const int* in_sizes, int n_in,
                              void* d_out, int out_size, void* d_ws, size_t ws_size,
                              hipStream_t stream) {
    const int T = 2, C = 128;
    const int N = in_sizes[0] / (T * C);   // 50000
    const int S = in_sizes[1];             // edge buffer reported element count
    const int Emax = S / 4;                // upper bound on edges per timestep

    const void* x_seq = d_in[0];
    const int* edges = (const int*)d_in[1];
    const void* W1 = d_in[2];
    const void* b1 = d_in[3];
    const void* W2 = d_in[4];
    const void* b2 = d_in[5];
    const void* Wc = d_in[6];
    const void* bc = d_in[7];

    // d_out is FLOAT32 (reference output dtype): [imp N][h_t0 N*C][h_t1 N*C]
    float* out = (float*)d_out;
    float* R0 = out + N;
    float* R1 = out + N + (size_t)N * C;

    // workspace ~34 MB
    char* p = (char*)d_ws;
    auto alloc = [&](size_t bytes) {
        char* r = p;
        p += (bytes + 255) & ~(size_t)255;
        return r;
    };
    int nb = (N + 255) / 256;
    int* flags = (int*)alloc(256);
    int* deg = (int*)alloc((size_t)N * 4);
    int* cursor = (int*)alloc((size_t)N * 4);
    int* off = (int*)alloc((size_t)(N + 1) * 4);
    int* btot = (int*)alloc((size_t)nb * 4);
    float* dinv = (float*)alloc((size_t)N * 4);
    int* ssrc = (int*)alloc((size_t)Emax * 4);
    u16* W1t = (u16*)alloc(128 * 128 * 2);
    u16* W2t = (u16*)alloc(128 * 128 * 2);
    u16* hsb = (u16*)alloc((size_t)N * C * 2);   // bf16 scaled GEMM output
    u16* hmb = (u16*)alloc((size_t)N * C * 2);   // bf16 layer-1 activation

    const int gE = (Emax + 255) / 256;
    const int gN4 = (N + 3) / 4;            // wave-per-node kernels
    const int gG = (N + 63) / 64;           // mfma gemm: block per 64 nodes
    const int gW = (128 * 128 + 255) / 256;

    detect_kernel<<<1, 64, 0, stream>>>(edges, (const u32*)x_seq, flags, S, N);
    prep_w<<<gW, 256, 0, stream>>>(W1, flags, W1t);
    prep_w<<<gW, 256, 0, stream>>>(W2, flags, W2t);

    for (int t = 0; t < T; ++t) {
        float* Rt = (t == 0) ? R0 : R1;     // final output region for this t
        // --- CSR build (shared by both conv layers of this timestep) ---
        hipMemsetAsync(deg, 0, (size_t)N * 4, stream);
        deg_kernel<<<gE, 256, 0, stream>>>(edges, flags, t, deg, N);
        scan_a<<<nb, 256, 0, stream>>>(deg, off, btot, N);
        scan_b<<<1, 256, 0, stream>>>(btot, nb);
        scan_c<<<nb, 256, 0, stream>>>(deg, btot, off, cursor, dinv, N);
        fill_kernel<<<gE, 256, 0, stream>>>(edges, flags, t, cursor, ssrc, N, Emax);

        // --- layer 1: hsb = dinv*(X_t @ W1); hmb = relu(gather)+b1 (bf16) ---
        gemm_mfma<<<gG, 256, 0, stream>>>(x_seq, (size_t)t * N * C, 1, W1t, flags,
                                          dinv, hsb, N);
        gather_kernel<<<gN4, 256, 0, stream>>>(hsb, off, deg, ssrc, dinv, b1, flags,
                                               (float*)nullptr, hmb, N, 1);

        // --- layer 2: hsb = dinv*(hmb @ W2); Rt = gather + b2 (f32) ---
        gemm_mfma<<<gG, 256, 0, stream>>>(hmb, 0, 0, W2t, flags, dinv, hsb, N);
        gather_kernel<<<gN4, 256, 0, stream>>>(hsb, off, deg, ssrc, dinv, b2, flags,
                                               Rt, (u16*)nullptr, N, 0);
    }

    importance_kernel<<<gN4, 256, 0, stream>>>(R1, Wc, bc, flags, out, N);
}